// Round 1
// baseline (3269.584 us; speedup 1.0000x reference)
//
#include <hip/hip_runtime.h>
#include <hip/hip_bf16.h>
#include <math.h>

#define HP 264
#define WP 264
#define NPIX (HP*WP)          // 69696
#define CH 64
#define BATCH 4
#define BCN (BATCH*CH)        // 256
#define H0 256
#define W0 256

// ---------------- twiddle tables ----------------
// csX[x*32+kx]  = (cos, sin) of 2*pi*x*kx/264          (for fwd-x; lanes vary kx)
// csXT[kx*264+x] same values transposed                 (for inv-x; lanes vary x)
// csY[y*64+j]   = (cos, sin) of 2*pi*y*ky/264, ky = j<32? j : 200+j   (232..263)
__global__ void init_tables(float2* __restrict__ csX, float2* __restrict__ csXT,
                            float2* __restrict__ csY) {
  int idx = blockIdx.x*256 + threadIdx.x;
  const float twopi_n = 6.28318530717958647692f / 264.0f;
  if (idx < 264*32) {
    int x = idx >> 5, kx = idx & 31;
    int ph = (x*kx) % 264;
    float s, c;
    sincosf(twopi_n * (float)ph, &s, &c);
    csX[idx] = make_float2(c, s);
    csXT[kx*264 + x] = make_float2(c, s);
  }
  if (idx < 264*64) {
    int y = idx >> 6, j = idx & 63;
    int ky = (j < 32) ? j : (200 + j);
    int ph = (y*ky) % 264;
    float s, c;
    sincosf(twopi_n * (float)ph, &s, &c);
    csY[idx] = make_float2(c, s);
  }
}

__device__ __forceinline__ float gelu_erf(float v) {
  return 0.5f * v * (1.0f + erff(v * 0.70710678118654752440f));
}

// ---------------- lift: [b,3,256,256]+coords -> gelu-MLP -> padded [b,64,264,264]
__global__ __launch_bounds__(256) void lift_kernel(
    const float* __restrict__ xin,
    const float* __restrict__ w1, const float* __restrict__ b1,
    const float* __restrict__ w2, const float* __restrict__ b2,
    float* __restrict__ xbuf) {
  int b = blockIdx.y;
  int flat = blockIdx.x*256 + threadIdx.x;
  if (flat >= NPIX) return;
  int y = flat / WP, x = flat - y*WP;
  float* outp = xbuf + (size_t)b*CH*NPIX + flat;
  if (y >= H0 || x >= W0) {
    for (int c = 0; c < CH; ++c) outp[c*NPIX] = 0.f;
    return;
  }
  float in[5];
  const float* xb = xin + ((size_t)b*3)*H0*W0 + y*W0 + x;
  in[0] = xb[0];
  in[1] = xb[H0*W0];
  in[2] = xb[2*H0*W0];
  in[3] = (float)y * (1.0f/255.0f);   // GX = linspace(0,1,256)[y]
  in[4] = (float)x * (1.0f/255.0f);   // GY
  float t[32];
  #pragma unroll
  for (int h = 0; h < 32; ++h) {
    float s = b1[h];
    #pragma unroll
    for (int i = 0; i < 5; ++i) s += w1[h*5+i]*in[i];
    t[h] = gelu_erf(s);
  }
  for (int c = 0; c < CH; ++c) {
    float s = b2[c];
    #pragma unroll
    for (int h = 0; h < 32; ++h) s += w2[c*32+h]*t[h];
    outp[c*NPIX] = s;
  }
}

// ---------------- fused conv1x1(64->64) -> mlp1(64->128)+gelu -> mlp2(128->64)
// 64-pixel tile per block, 256 threads, weights via wave-uniform scalar loads.
__global__ __launch_bounds__(256) void convmlp_kernel(
    const float* __restrict__ X, float* __restrict__ Hb,
    const float* __restrict__ Wc, const float* __restrict__ cb,
    const float* __restrict__ W1, const float* __restrict__ b1,
    const float* __restrict__ W2, const float* __restrict__ b2) {
  __shared__ float sA[128*64];   // input tile, later gelu(mlp1) tile
  __shared__ float sB[64*64];    // conv output tile
  int blk = blockIdx.x;                 // 0..4355
  int b = blk / 1089;
  int flat0 = (blk - b*1089) * 64;
  int tid = threadIdx.x;
  int p = tid & 63;
  int cg = __builtin_amdgcn_readfirstlane(tid >> 6);  // 0..3, wave-uniform
  const float* xb = X + (size_t)b*CH*NPIX + flat0;
  #pragma unroll
  for (int i = 0; i < 16; ++i) {
    int idx = i*256 + tid;              // idx = ci*64 + pp
    int ci = idx >> 6, pp = idx & 63;
    sA[idx] = xb[ci*NPIX + pp];
  }
  __syncthreads();
  // stage 1: conv 64->64
  float acc0[16];
  #pragma unroll
  for (int i = 0; i < 16; ++i) acc0[i] = cb[cg*16+i];
  for (int ci = 0; ci < 64; ++ci) {
    float xv = sA[ci*64+p];
    #pragma unroll
    for (int i = 0; i < 16; ++i) acc0[i] += xv * Wc[(cg*16+i)*64+ci];
  }
  #pragma unroll
  for (int i = 0; i < 16; ++i) sB[(cg*16+i)*64+p] = acc0[i];
  __syncthreads();
  // stage 2: mlp1 64->128 + gelu (overwrites sA; safe: all stage-1 reads done)
  float a1[32];
  #pragma unroll
  for (int j = 0; j < 32; ++j) a1[j] = b1[cg*32+j];
  for (int ci = 0; ci < 64; ++ci) {
    float xv = sB[ci*64+p];
    #pragma unroll
    for (int j = 0; j < 32; ++j) a1[j] += xv * W1[(cg*32+j)*64+ci];
  }
  #pragma unroll
  for (int j = 0; j < 32; ++j) sA[(cg*32+j)*64+p] = gelu_erf(a1[j]);
  __syncthreads();
  // stage 3: mlp2 128->64
  float acc2[16];
  #pragma unroll
  for (int i = 0; i < 16; ++i) acc2[i] = b2[cg*16+i];
  for (int ci = 0; ci < 128; ++ci) {
    float xv = sA[ci*64+p];
    #pragma unroll
    for (int i = 0; i < 16; ++i) acc2[i] += xv * W2[(cg*16+i)*128+ci];
  }
  float* hb = Hb + (size_t)b*CH*NPIX + flat0;
  #pragma unroll
  for (int i = 0; i < 16; ++i) hb[(cg*16+i)*NPIX + p] = acc2[i];
}

// ---------------- forward DFT along x: F1[row,kx] = sum_x X[row,x] e^{-i 2pi x kx/264}
__global__ __launch_bounds__(256) void fwd_x_kernel(const float* __restrict__ X,
    float2* __restrict__ F1, const float2* __restrict__ csX) {
  __shared__ float2 sCS[264*32];   // 67.6 KB
  __shared__ float  sX[8*264];     // 8.4 KB
  int tid = threadIdx.x;
  #pragma unroll
  for (int i = 0; i < 33; ++i) sCS[i*256+tid] = csX[i*256+tid];
  int row0 = blockIdx.x * 8;       // rows = bc*264 + y, 67584 total
  const float* xb = X + (size_t)row0*264;
  for (int i = 0; i < 9; ++i) {
    int idx = i*256 + tid;
    if (idx < 8*264) sX[idx] = xb[idx];
  }
  __syncthreads();
  int kx = tid & 31;
  int rl = tid >> 5;
  float re = 0.f, im = 0.f;
  for (int x = 0; x < 264; ++x) {
    float xv = sX[rl*264 + x];
    float2 cs = sCS[x*32 + kx];
    re += xv * cs.x;
    im -= xv * cs.y;
  }
  F1[(size_t)(row0+rl)*32 + kx] = make_float2(re, im);
}

// ---------------- forward DFT along y (64 kept ky): complex x e^{-i theta}
__global__ __launch_bounds__(256) void fwd_y_kernel(const float2* __restrict__ F1,
    float2* __restrict__ F2, const float2* __restrict__ csY) {
  __shared__ float2 sCS[264*8];
  int tid = threadIdx.x;
  int bc = blockIdx.y;
  int ky0 = blockIdx.x * 8;
  for (int i = 0; i < 9; ++i) {
    int idx = i*256 + tid;
    if (idx < 264*8) {
      int yy = idx >> 3, jl = idx & 7;
      sCS[idx] = csY[yy*64 + ky0 + jl];
    }
  }
  __syncthreads();
  int kx = tid & 31;
  int kyl = tid >> 5;
  const float2* f1 = F1 + (size_t)bc*8448;
  float re = 0.f, im = 0.f;
  for (int y = 0; y < 264; ++y) {
    float2 f = f1[y*32 + kx];
    float2 cs = sCS[y*8 + kyl];
    re += f.x*cs.x + f.y*cs.y;    // (fr+ifi)(c-is)
    im += f.y*cs.x - f.x*cs.y;
  }
  F2[((size_t)bc*64 + ky0 + kyl)*32 + kx] = make_float2(re, im);
}

// ---------------- per-mode channel mixing: S[b,co,mode] = sum_ci F2[b,ci,mode]*W[ci,co,mode]
__global__ __launch_bounds__(256) void mix_kernel(const float2* __restrict__ F2,
    float2* __restrict__ S,
    const float* __restrict__ w1r, const float* __restrict__ w1i,
    const float* __restrict__ w2r, const float* __restrict__ w2i) {
  int tid = threadIdx.x;
  int m = tid & 63;
  int cl = tid >> 6;
  int mode = blockIdx.x*64 + m;        // 0..2047 = kyi*32+kx ; uniform block halves
  int co = blockIdx.y*4 + cl;
  int b = blockIdx.z;
  int moff = mode & 1023;
  const float* wr = ((mode < 1024) ? w1r : w2r) + co*1024 + moff;
  const float* wi = ((mode < 1024) ? w1i : w2i) + co*1024 + moff;
  const float2* f2 = F2 + (size_t)b*CH*2048 + mode;
  float sr = 0.f, si = 0.f;
  for (int ci = 0; ci < 64; ++ci) {
    float2 f = f2[(size_t)ci*2048];
    float wrv = wr[(size_t)ci*65536];
    float wiv = wi[(size_t)ci*65536];
    sr += f.x*wrv - f.y*wiv;
    si += f.x*wiv + f.y*wrv;
  }
  S[((size_t)b*CH + co)*2048 + mode] = make_float2(sr, si);
}

// ---------------- inverse DFT along y: Z[bc,y,kx] = sum_kyi S[bc,kyi,kx] e^{+i theta}
__global__ __launch_bounds__(256) void inv_y_kernel(const float2* __restrict__ S,
    float2* __restrict__ Z, const float2* __restrict__ csY) {
  __shared__ float2 sS[64*32];
  __shared__ float2 sCS[8*64];
  int tid = threadIdx.x;
  int bc = blockIdx.y;
  int y0 = blockIdx.x * 8;
  #pragma unroll
  for (int i = 0; i < 8; ++i) sS[i*256+tid] = S[(size_t)bc*2048 + i*256 + tid];
  #pragma unroll
  for (int i = 0; i < 2; ++i) {
    int idx = i*256+tid;
    int yy = idx >> 6, j = idx & 63;
    sCS[idx] = csY[(y0+yy)*64 + j];
  }
  __syncthreads();
  int kx = tid & 31;
  int yl = tid >> 5;
  float zr = 0.f, zi = 0.f;
  for (int j = 0; j < 64; ++j) {
    float2 sv = sS[j*32 + kx];
    float2 cs = sCS[yl*64 + j];
    zr += sv.x*cs.x - sv.y*cs.y;    // (sr+isi)(c+is)
    zi += sv.x*cs.y + sv.y*cs.x;
  }
  Z[((size_t)bc*264 + y0 + yl)*32 + kx] = make_float2(zr, zi);
}

// ---------------- inverse rfft along x + combine with mlp branch
// out = Hb + (1/(264*264)) * [ Re(z0) + 2*sum_{kx=1..31} Re(z_kx e^{+i 2pi kx x/264}) ]
__global__ __launch_bounds__(256) void inv_x_kernel(const float2* __restrict__ Z,
    const float* __restrict__ Hb, float* __restrict__ Xout, float* __restrict__ Dout,
    const float2* __restrict__ csXT, int last) {
  __shared__ float2 sCS[32*264];   // 67.6 KB
  int tid = threadIdx.x;
  #pragma unroll
  for (int i = 0; i < 33; ++i) sCS[i*256+tid] = csXT[i*256+tid];
  __syncthreads();
  int bc = blockIdx.y;
  int flat = blockIdx.x*256 + tid;
  if (flat >= NPIX) return;
  int y = flat / 264, x = flat - y*264;
  const float2* zp = Z + ((size_t)bc*264 + y)*32;
  float2 z0 = zp[0];
  float2 cs0 = sCS[x];
  float acc = z0.x*cs0.x - z0.y*cs0.y;   // imag(z0) dropped per irfft semantics
  for (int kx = 1; kx < 32; ++kx) {
    float2 z = zp[kx];
    float2 cs = sCS[kx*264 + x];
    acc += 2.0f*(z.x*cs.x - z.y*cs.y);
  }
  float r = Hb[(size_t)bc*NPIX + flat] + acc * (1.0f/69696.0f);
  if (last) {
    if (y < 256 && x < 256) Dout[(size_t)bc*65536 + y*256 + x] = r;
  } else {
    Xout[(size_t)bc*NPIX + flat] = r;
  }
}

extern "C" void kernel_launch(void* const* d_in, const int* in_sizes, int n_in,
                              void* d_out, int out_size, void* d_ws, size_t ws_size,
                              hipStream_t stream) {
  (void)in_sizes; (void)n_in; (void)out_size; (void)ws_size;
  const float* x_in   = (const float*)d_in[0];
  const float* lw1    = (const float*)d_in[1];
  const float* lb1    = (const float*)d_in[2];
  const float* lw2    = (const float*)d_in[3];
  const float* lb2    = (const float*)d_in[4];
  const float* conv_w = (const float*)d_in[5];
  const float* conv_b = (const float*)d_in[6];
  const float* mlp_w1 = (const float*)d_in[7];
  const float* mlp_b1 = (const float*)d_in[8];
  const float* mlp_w2 = (const float*)d_in[9];
  const float* mlp_b2 = (const float*)d_in[10];
  const float* sw1r   = (const float*)d_in[11];
  const float* sw1i   = (const float*)d_in[12];
  const float* sw2r   = (const float*)d_in[13];
  const float* sw2i   = (const float*)d_in[14];
  float* dout = (float*)d_out;

  // workspace carve-up (floats): total ~42.2M floats = 169 MB
  float* ws = (float*)d_ws;
  size_t off = 0;
  float*  xbuf = ws + off;          off += (size_t)BCN*NPIX;       // 17,842,176
  float*  hbuf = ws + off;          off += (size_t)BCN*NPIX;       // 17,842,176
  float2* F1   = (float2*)(ws+off); off += (size_t)BCN*264*32*2;   // also Z (aliased)
  float2* F2   = (float2*)(ws+off); off += (size_t)BCN*2048*2;
  float2* S    = (float2*)(ws+off); off += (size_t)BCN*2048*2;
  float2* csX  = (float2*)(ws+off); off += 264*32*2;
  float2* csXT = (float2*)(ws+off); off += 264*32*2;
  float2* csY  = (float2*)(ws+off); off += 264*64*2;

  init_tables<<<66, 256, 0, stream>>>(csX, csXT, csY);
  lift_kernel<<<dim3(273, 4), 256, 0, stream>>>(x_in, lw1, lb1, lw2, lb2, xbuf);

  for (int k = 0; k < 3; ++k) {
    convmlp_kernel<<<4356, 256, 0, stream>>>(xbuf, hbuf,
        conv_w + k*4096, conv_b + k*64,
        mlp_w1 + k*8192, mlp_b1 + k*128,
        mlp_w2 + k*8192, mlp_b2 + k*64);
    fwd_x_kernel<<<8448, 256, 0, stream>>>(xbuf, F1, csX);
    fwd_y_kernel<<<dim3(8, 256), 256, 0, stream>>>(F1, F2, csY);
    mix_kernel<<<dim3(32, 16, 4), 256, 0, stream>>>(F2, S,
        sw1r + (size_t)k*4194304, sw1i + (size_t)k*4194304,
        sw2r + (size_t)k*4194304, sw2i + (size_t)k*4194304);
    inv_y_kernel<<<dim3(33, 256), 256, 0, stream>>>(S, F1 /*Z aliases F1*/, csY);
    inv_x_kernel<<<dim3(273, 256), 256, 0, stream>>>(F1, hbuf, xbuf, dout, csXT, (k==2)?1:0);
  }
}

// Round 2
// 2453.053 us; speedup vs baseline: 1.3329x; 1.3329x over previous
//
#include <hip/hip_runtime.h>
#include <math.h>

#define HP 264
#define WP 264
#define NPIX (HP*WP)          // 69696
#define CH 64
#define BATCH 4
#define BCN (BATCH*CH)        // 256
#define NROWS (BCN*HP)        // 67584
#define H0 256
#define W0 256

// ---------------- tables ----------------
// BX[x*64+k]  : fwd-x DFT. k=2m -> cos(2pi*x*m/264); k=2m+1 -> -sin(...)
// BI[k*264+x] : inv-x irfft. k=2m -> sc*cos; k=2m+1 -> -sc*sin; BI[1][x]=0.
//               sc = (m==0 ? 1 : 2)/69696  (2x for hermitian fold, 1/N for irfft2 norm)
// csY[y*64+j]  float2 (cos,sin) of 2pi*y*ky_j/264, ky_j = j<32 ? j : 200+j
// csYT[j*264+y] same values transposed (for inv_y coalesced lane reads)
__global__ void init_tables(float* __restrict__ BX, float* __restrict__ BI,
                            float2* __restrict__ csY, float2* __restrict__ csYT) {
  int idx = blockIdx.x*256 + threadIdx.x;
  if (idx >= 264*64) return;
  const float w = 6.28318530717958647692f / 264.0f;
  {
    int x = idx >> 6, k = idx & 63;
    int m = k >> 1;
    float s, c; sincosf(w * (float)((x*m) % 264), &s, &c);
    BX[idx] = (k & 1) ? -s : c;
    float sc = (m ? 2.0f : 1.0f) / 69696.0f;
    float v = (k & 1) ? -sc*s : sc*c;
    if (k == 1) v = 0.f;
    BI[(size_t)k*264 + x] = v;
  }
  {
    int y = idx >> 6, j = idx & 63;
    int ky = (j < 32) ? j : (200 + j);
    float s, c; sincosf(w * (float)((y*ky) % 264), &s, &c);
    csY[y*64 + j] = make_float2(c, s);
    csYT[j*264 + y] = make_float2(c, s);
  }
}

__device__ __forceinline__ float gelu_erf(float v) {
  return 0.5f * v * (1.0f + erff(v * 0.70710678118654752440f));
}

// ---------------- lift: [b,3,256,256]+coords -> gelu-MLP -> padded [b,64,264,264]
__global__ __launch_bounds__(256) void lift_kernel(
    const float* __restrict__ xin,
    const float* __restrict__ w1, const float* __restrict__ b1,
    const float* __restrict__ w2, const float* __restrict__ b2,
    float* __restrict__ xbuf) {
  int b = blockIdx.y;
  int flat = blockIdx.x*256 + threadIdx.x;
  if (flat >= NPIX) return;
  int y = flat / WP, x = flat - y*WP;
  float* outp = xbuf + (size_t)b*CH*NPIX + flat;
  if (y >= H0 || x >= W0) {
    for (int c = 0; c < CH; ++c) outp[c*NPIX] = 0.f;
    return;
  }
  float in[5];
  const float* xb = xin + ((size_t)b*3)*H0*W0 + y*W0 + x;
  in[0] = xb[0];
  in[1] = xb[H0*W0];
  in[2] = xb[2*H0*W0];
  in[3] = (float)y * (1.0f/255.0f);
  in[4] = (float)x * (1.0f/255.0f);
  float t[32];
  #pragma unroll
  for (int h = 0; h < 32; ++h) {
    float s = b1[h];
    #pragma unroll
    for (int i = 0; i < 5; ++i) s += w1[h*5+i]*in[i];
    t[h] = gelu_erf(s);
  }
  for (int c = 0; c < CH; ++c) {
    float s = b2[c];
    #pragma unroll
    for (int h = 0; h < 32; ++h) s += w2[c*32+h]*t[h];
    outp[c*NPIX] = s;
  }
}

// ---------------- fused conv1x1(64->64) -> mlp1(64->128)+gelu -> mlp2(128->64)
__global__ __launch_bounds__(256) void convmlp_kernel(
    const float* __restrict__ X, float* __restrict__ Hb,
    const float* __restrict__ Wc, const float* __restrict__ cb,
    const float* __restrict__ W1, const float* __restrict__ b1,
    const float* __restrict__ W2, const float* __restrict__ b2) {
  __shared__ float sA[128*64];
  __shared__ float sB[64*64];
  int blk = blockIdx.x;
  int b = blk / 1089;
  int flat0 = (blk - b*1089) * 64;
  int tid = threadIdx.x;
  int p = tid & 63;
  int cg = __builtin_amdgcn_readfirstlane(tid >> 6);
  const float* xb = X + (size_t)b*CH*NPIX + flat0;
  #pragma unroll
  for (int i = 0; i < 16; ++i) {
    int idx = i*256 + tid;
    int ci = idx >> 6, pp = idx & 63;
    sA[idx] = xb[ci*NPIX + pp];
  }
  __syncthreads();
  float acc0[16];
  #pragma unroll
  for (int i = 0; i < 16; ++i) acc0[i] = cb[cg*16+i];
  for (int ci = 0; ci < 64; ++ci) {
    float xv = sA[ci*64+p];
    #pragma unroll
    for (int i = 0; i < 16; ++i) acc0[i] += xv * Wc[(cg*16+i)*64+ci];
  }
  #pragma unroll
  for (int i = 0; i < 16; ++i) sB[(cg*16+i)*64+p] = acc0[i];
  __syncthreads();
  float a1[32];
  #pragma unroll
  for (int j = 0; j < 32; ++j) a1[j] = b1[cg*32+j];
  for (int ci = 0; ci < 64; ++ci) {
    float xv = sB[ci*64+p];
    #pragma unroll
    for (int j = 0; j < 32; ++j) a1[j] += xv * W1[(cg*32+j)*64+ci];
  }
  #pragma unroll
  for (int j = 0; j < 32; ++j) sA[(cg*32+j)*64+p] = gelu_erf(a1[j]);
  __syncthreads();
  float acc2[16];
  #pragma unroll
  for (int i = 0; i < 16; ++i) acc2[i] = b2[cg*16+i];
  for (int ci = 0; ci < 128; ++ci) {
    float xv = sA[ci*64+p];
    #pragma unroll
    for (int i = 0; i < 16; ++i) acc2[i] += xv * W2[(cg*16+i)*128+ci];
  }
  float* hb = Hb + (size_t)b*CH*NPIX + flat0;
  #pragma unroll
  for (int i = 0; i < 16; ++i) hb[(cg*16+i)*NPIX + p] = acc2[i];
}

// ---------------- fwd-x DFT: F1[r][k] = sum_x X[r][x]*BX[x][k]
// lane = row; acc[64] in VGPRs; BX rows wave-uniform -> s_load.
__global__ __launch_bounds__(128) void fwd_x_kernel(const float* __restrict__ X,
    float* __restrict__ F1, const float* __restrict__ BX) {
  int r = blockIdx.x*128 + threadIdx.x;
  const float* xr = X + (size_t)r*264;
  float acc[64];
  #pragma unroll
  for (int k = 0; k < 64; ++k) acc[k] = 0.f;
  float4 u = ((const float4*)xr)[0];
  float4 v = ((const float4*)xr)[1];
  #pragma unroll 1
  for (int xc = 0; xc < 33; ++xc) {
    int nc = (xc < 32) ? xc + 1 : 32;
    float4 nu = ((const float4*)xr)[nc*2];
    float4 nv = ((const float4*)xr)[nc*2+1];
    float xv[8] = {u.x,u.y,u.z,u.w,v.x,v.y,v.z,v.w};
    #pragma unroll
    for (int i = 0; i < 8; ++i) {
      const float* B = BX + (xc*8+i)*64;
      #pragma unroll
      for (int k = 0; k < 64; ++k) acc[k] = fmaf(xv[i], B[k], acc[k]);
    }
    u = nu; v = nv;
  }
  float* fr = F1 + (size_t)r*64;
  #pragma unroll
  for (int q = 0; q < 16; ++q)
    ((float4*)fr)[q] = make_float4(acc[4*q],acc[4*q+1],acc[4*q+2],acc[4*q+3]);
}

// ---------------- fwd-y DFT: F2[bc][j][k] = sum_y F1[bc][y][k'] * twiddle(y,ky_j)
// lane = j (output ky); per-lane (c,s); F1 row wave-uniform -> s_load.
// 4 waves split y-range, LDS combine.
__global__ __launch_bounds__(256) void fwd_y_kernel(const float* __restrict__ F1,
    float* __restrict__ F2, const float2* __restrict__ csY) {
  __shared__ float sT[4][64][68];
  int tid = threadIdx.x, lane = tid & 63, w = tid >> 6;
  int bc = blockIdx.x;
  float acc[64];
  #pragma unroll
  for (int k = 0; k < 64; ++k) acc[k] = 0.f;
  const float* f1b = F1 + (size_t)bc*264*64;
  for (int y = w*66; y < (w+1)*66; ++y) {
    float2 cs = csY[y*64 + lane];
    float c = cs.x, s = cs.y, ns = -s;
    const float* fr = f1b + y*64;
    #pragma unroll
    for (int kx = 0; kx < 32; ++kx) {
      float fre = fr[2*kx], fim = fr[2*kx+1];
      acc[2*kx]   = fmaf(c, fre, fmaf(s,  fim, acc[2*kx]));
      acc[2*kx+1] = fmaf(c, fim, fmaf(ns, fre, acc[2*kx+1]));
    }
  }
  #pragma unroll
  for (int k = 0; k < 64; ++k) sT[w][lane][k] = acc[k];
  __syncthreads();
  int j = tid >> 2, k0 = (tid & 3) * 16;
  float* out = F2 + (size_t)bc*4096 + j*64 + k0;
  #pragma unroll
  for (int k = 0; k < 16; ++k)
    out[k] = sT[0][j][k0+k] + sT[1][j][k0+k] + sT[2][j][k0+k] + sT[3][j][k0+k];
}

// ---------------- per-mode channel mixing (unchanged math)
__global__ __launch_bounds__(256) void mix_kernel(const float2* __restrict__ F2,
    float2* __restrict__ S,
    const float* __restrict__ w1r, const float* __restrict__ w1i,
    const float* __restrict__ w2r, const float* __restrict__ w2i) {
  int tid = threadIdx.x;
  int m = tid & 63;
  int cl = tid >> 6;
  int mode = blockIdx.x*64 + m;
  int co = blockIdx.y*4 + cl;
  int b = blockIdx.z;
  int moff = mode & 1023;
  const float* wr = ((mode < 1024) ? w1r : w2r) + co*1024 + moff;
  const float* wi = ((mode < 1024) ? w1i : w2i) + co*1024 + moff;
  const float2* f2 = F2 + (size_t)b*CH*2048 + mode;
  float sr = 0.f, si = 0.f;
  for (int ci = 0; ci < 64; ++ci) {
    float2 f = f2[(size_t)ci*2048];
    float wrv = wr[(size_t)ci*65536];
    float wiv = wi[(size_t)ci*65536];
    sr += f.x*wrv - f.y*wiv;
    si += f.x*wiv + f.y*wrv;
  }
  S[((size_t)b*CH + co)*2048 + mode] = make_float2(sr, si);
}

// ---------------- inv-y DFT: Z[bc][y][k] = sum_j S[bc][j][k'] * e^{+i theta(y,ky_j)}
// lane = y; per-lane (c,s) from transposed table; S row wave-uniform -> s_load.
__global__ __launch_bounds__(64) void inv_y_kernel(const float* __restrict__ S,
    float* __restrict__ Z, const float2* __restrict__ csYT) {
  int bc = blockIdx.y;
  int y = blockIdx.x*64 + threadIdx.x;   // 0..319
  int yy = (y < 264) ? y : 263;
  float acc[64];
  #pragma unroll
  for (int k = 0; k < 64; ++k) acc[k] = 0.f;
  const float* sb = S + (size_t)bc*4096;
  for (int j = 0; j < 64; ++j) {
    float2 cs = csYT[j*264 + yy];
    float c = cs.x, s = cs.y, ns = -s;
    const float* sr = sb + j*64;
    #pragma unroll
    for (int kx = 0; kx < 32; ++kx) {
      float sre = sr[2*kx], sim = sr[2*kx+1];
      acc[2*kx]   = fmaf(c, sre, fmaf(ns, sim, acc[2*kx]));
      acc[2*kx+1] = fmaf(s, sre, fmaf(c,  sim, acc[2*kx+1]));
    }
  }
  if (y < 264) {
    float* zr = Z + ((size_t)bc*264 + y)*64;
    #pragma unroll
    for (int q = 0; q < 16; ++q)
      ((float4*)zr)[q] = make_float4(acc[4*q],acc[4*q+1],acc[4*q+2],acc[4*q+3]);
  }
}

// ---------------- inv-x irfft + Hb add + store (crop on last layer)
// lane = row; z-row (64 floats) in VGPRs; BI rows wave-uniform -> s_load.
__global__ __launch_bounds__(128) void inv_x_kernel(const float* __restrict__ Z,
    const float* __restrict__ Hb, float* __restrict__ Xout, float* __restrict__ Dout,
    const float* __restrict__ BI, int last) {
  int r = blockIdx.x*128 + threadIdx.x;
  int xh = blockIdx.y;              // 0: x in [0,128); 1: x in [128,264)
  float a[64];
  const float4* zp = (const float4*)(Z + (size_t)r*64);
  #pragma unroll
  for (int q = 0; q < 16; ++q) {
    float4 t = zp[q];
    a[4*q] = t.x; a[4*q+1] = t.y; a[4*q+2] = t.z; a[4*q+3] = t.w;
  }
  int y = r % 264;
  int bc = r / 264;
  const float* hbr = Hb + (size_t)r*264;
  float* xo = Xout + (size_t)r*264;
  float* dor = Dout + ((size_t)bc*256 + y)*256;
  #pragma unroll 1
  for (int cch = 0; cch < 4; ++cch) {
    int x0 = xh*128 + cch*32;
    float acc[32];
    #pragma unroll
    for (int s = 0; s < 32; ++s) acc[s] = 0.f;
    #pragma unroll
    for (int k = 0; k < 64; ++k) {
      const float* B = BI + (size_t)k*264 + x0;
      #pragma unroll
      for (int s = 0; s < 32; ++s) acc[s] = fmaf(a[k], B[s], acc[s]);
    }
    if (!last) {
      #pragma unroll
      for (int q = 0; q < 8; ++q) {
        float4 h = ((const float4*)(hbr + x0))[q];
        ((float4*)(xo + x0))[q] =
          make_float4(h.x+acc[4*q], h.y+acc[4*q+1], h.z+acc[4*q+2], h.w+acc[4*q+3]);
      }
    } else if (y < 256) {
      #pragma unroll
      for (int q = 0; q < 8; ++q) {
        float4 h = ((const float4*)(hbr + x0))[q];
        ((float4*)(dor + x0))[q] =
          make_float4(h.x+acc[4*q], h.y+acc[4*q+1], h.z+acc[4*q+2], h.w+acc[4*q+3]);
      }
    }
  }
  if (xh == 1 && !last) {          // tail x in [256,264), only needed mid-stack
    float acc[8];
    #pragma unroll
    for (int s = 0; s < 8; ++s) acc[s] = 0.f;
    #pragma unroll
    for (int k = 0; k < 64; ++k) {
      const float* B = BI + (size_t)k*264 + 256;
      #pragma unroll
      for (int s = 0; s < 8; ++s) acc[s] = fmaf(a[k], B[s], acc[s]);
    }
    #pragma unroll
    for (int q = 0; q < 2; ++q) {
      float4 h = ((const float4*)(hbr + 256))[q];
      ((float4*)(xo + 256))[q] =
        make_float4(h.x+acc[4*q], h.y+acc[4*q+1], h.z+acc[4*q+2], h.w+acc[4*q+3]);
    }
  }
}

extern "C" void kernel_launch(void* const* d_in, const int* in_sizes, int n_in,
                              void* d_out, int out_size, void* d_ws, size_t ws_size,
                              hipStream_t stream) {
  (void)in_sizes; (void)n_in; (void)out_size; (void)ws_size;
  const float* x_in   = (const float*)d_in[0];
  const float* lw1    = (const float*)d_in[1];
  const float* lb1    = (const float*)d_in[2];
  const float* lw2    = (const float*)d_in[3];
  const float* lb2    = (const float*)d_in[4];
  const float* conv_w = (const float*)d_in[5];
  const float* conv_b = (const float*)d_in[6];
  const float* mlp_w1 = (const float*)d_in[7];
  const float* mlp_b1 = (const float*)d_in[8];
  const float* mlp_w2 = (const float*)d_in[9];
  const float* mlp_b2 = (const float*)d_in[10];
  const float* sw1r   = (const float*)d_in[11];
  const float* sw1i   = (const float*)d_in[12];
  const float* sw2r   = (const float*)d_in[13];
  const float* sw2i   = (const float*)d_in[14];
  float* dout = (float*)d_out;

  float* ws = (float*)d_ws;
  size_t off = 0;
  float*  xbuf = ws + off;          off += (size_t)BCN*NPIX;    // 17,842,176
  float*  hbuf = ws + off;          off += (size_t)BCN*NPIX;    // 17,842,176
  float*  F1   = ws + off;          off += (size_t)NROWS*64;    // 4,325,376 (also Z)
  float*  F2   = ws + off;          off += (size_t)BCN*4096;    // 1,048,576
  float*  S    = ws + off;          off += (size_t)BCN*4096;    // 1,048,576
  float*  BX   = ws + off;          off += 264*64;
  float*  BI   = ws + off;          off += 264*64;
  float2* csY  = (float2*)(ws+off); off += 264*64*2;
  float2* csYT = (float2*)(ws+off); off += 264*64*2;

  init_tables<<<66, 256, 0, stream>>>(BX, BI, csY, csYT);
  lift_kernel<<<dim3(273, 4), 256, 0, stream>>>(x_in, lw1, lb1, lw2, lb2, xbuf);

  for (int k = 0; k < 3; ++k) {
    convmlp_kernel<<<4356, 256, 0, stream>>>(xbuf, hbuf,
        conv_w + k*4096, conv_b + k*64,
        mlp_w1 + k*8192, mlp_b1 + k*128,
        mlp_w2 + k*8192, mlp_b2 + k*64);
    fwd_x_kernel<<<528, 128, 0, stream>>>(xbuf, F1, BX);
    fwd_y_kernel<<<256, 256, 0, stream>>>(F1, F2, csY);
    mix_kernel<<<dim3(32, 16, 4), 256, 0, stream>>>((const float2*)F2, (float2*)S,
        sw1r + (size_t)k*4194304, sw1i + (size_t)k*4194304,
        sw2r + (size_t)k*4194304, sw2i + (size_t)k*4194304);
    inv_y_kernel<<<dim3(5, 256), 64, 0, stream>>>(S, F1 /*Z aliases F1*/, csYT);
    inv_x_kernel<<<dim3(528, 2), 128, 0, stream>>>(F1, hbuf, xbuf, dout, BI, (k==2)?1:0);
  }
}